// Round 11
// baseline (420.967 us; speedup 1.0000x reference)
//
#include <hip/hip_runtime.h>
#include <hip/hip_bf16.h>

#define NN 100000
#define EE 1600000
#define NB_SCAN 391   // ceil(NN/256)
#define HB 782        // hist/scatter block count (8 edges/thread)
#define GB 4096       // gather blocks (4 waves each)

typedef __hip_bfloat16 bf16_t;
typedef int int4v __attribute__((ext_vector_type(4)));
typedef float f4 __attribute__((ext_vector_type(4)));
typedef unsigned int u4v __attribute__((ext_vector_type(4)));

// ---- workspace layout (float offsets) ----
#define PARB  600000       // params fp32 4465
#define EMB   604480       // N*32 bf16 (N*16 u32)
#define PBUF  3804480      // N*32 bf16 P'
#define QBUF  7004480      // N*32 bf16 Q
#define ABUF  10204480     // N*32 agg bf16; aliased as rank[EE] before gather
#define SOFF  13404480     // stats fp32 [0:128), flag@128(int), done@132(int)
#define DEG   (SOFF + 256)           // deg, then FINAL row pointers
#define ROWP  (DEG + 100000)         // chunk-local exclusive scan
#define BSUM  (ROWP + 100002)
#define SRCL  (BSUM + 512)

// ---- param offsets inside PARB ----
#define O_WCONT 0
#define O_BCONT 96
#define O_TCHRG 112
#define O_TPDG  136
#define O_TPV   192
#define O_WCAT  256
#define O_BCAT  640
#define O_WENC  656
#define O_BENC  1680
#define O_GALL  1712
#define O_BEALL 1744
#define O_WMSG  1776
#define O_BMSG  3824
#define O_GCONV 3856
#define O_BECONV 3888
#define O_WOUT1 3920
#define O_BOUT1 4432
#define O_WOUT2 4448
#define O_BOUT2 4464
#define NPAR    4465

__device__ __forceinline__ float bf(unsigned u) {
    return __uint_as_float(u << 16);
}
__device__ __forceinline__ unsigned short f2bf(float x) {
    __hip_bfloat16 h = __float2bfloat16(x);   // RNE
    return *reinterpret_cast<unsigned short*>(&h);
}
__device__ __forceinline__ unsigned pack2(float a, float b) {
    return (unsigned)f2bf(a) | ((unsigned)f2bf(b) << 16);
}
__device__ __forceinline__ f4 elu4(f4 v) {
    f4 r;
    r.x = v.x > 0.0f ? v.x : expm1f(v.x);
    r.y = v.y > 0.0f ? v.y : expm1f(v.y);
    r.z = v.z > 0.0f ? v.z : expm1f(v.z);
    r.w = v.w > 0.0f ? v.w : expm1f(v.w);
    return r;
}
// unpack u4v (8 bf16) -> two f4
__device__ __forceinline__ void unpack8(u4v q, f4& a, f4& b) {
    a.x = bf(q.x & 0xFFFFu); a.y = bf(q.x >> 16);
    a.z = bf(q.y & 0xFFFFu); a.w = bf(q.y >> 16);
    b.x = bf(q.z & 0xFFFFu); b.y = bf(q.z >> 16);
    b.z = bf(q.w & 0xFFFFu); b.w = bf(q.w >> 16);
}

// ---------------- init: zero deg/stats/flags; block 0 detects dtype + converts params ----------------
struct InitArgs {
    const void* p[19];
    float*      par;
    int*        deg;
    float*      stats;
    int*        flagp;
};

__global__ __launch_bounds__(256) void k_init(InitArgs a)
{
    __shared__ int sflag;
    const int offs[20] = {O_WCONT,O_BCONT,O_TCHRG,O_TPDG,O_TPV,O_WCAT,O_BCAT,O_WENC,
                          O_BENC,O_GALL,O_BEALL,O_WMSG,O_BMSG,O_GCONV,O_BECONV,
                          O_WOUT1,O_BOUT1,O_WOUT2,O_BOUT2,NPAR};
    int b = blockIdx.x, tid = threadIdx.x;
    int g = b * 256 + tid;
    if (g < NN) a.deg[g] = 0;
    if (b == 0) {
        if (tid < 136) a.stats[tid] = 0.0f;   // stats + flag + done
        __syncthreads();
        int bad = 0;
        if (tid < 64) {
            const unsigned short* w = (const unsigned short*)a.p[7];  // W_enc
            for (int i = tid; i < 1024; i += 64) {
                unsigned e = (w[i] >> 7) & 0xFFu;
                if (e >= 137u) bad = 1;   // |v|>=2^10 as bf16 -> tensors are really f32
            }
        }
        unsigned long long m = __ballot(bad);
        if (tid == 0) { sflag = (m != 0ull) ? 1 : 0; *a.flagp = sflag; }
        __syncthreads();
        int f32 = sflag;
        for (int i = tid; i < NPAR; i += 256) {
            int t = 0;
            while (offs[t + 1] <= i) t++;
            int l = i - offs[t];
            const void* s = a.p[t];
            a.par[i] = f32 ? ((const float*)s)[l] : bf(((const unsigned short*)s)[l]);
        }
    }
}

// ---------------- fused A: hist (b%3!=0) | embed->bf16 (b%3==0) ----------------
__global__ __launch_bounds__(256, 1) void k_fusedA(
    const int* __restrict__ eidx, int* __restrict__ deg, int* __restrict__ rank,
    const void* __restrict__ xc, const int* __restrict__ x_cat,
    const float* __restrict__ par, const int* __restrict__ flag,
    unsigned int* __restrict__ embb)
{
    __shared__ f4 sWc4[24];
    __shared__ f4 sbc4[4];
    __shared__ f4 sTc4[6], sTp4[14], sTv4[16];
    __shared__ f4 sWcat4[96];
    __shared__ f4 sbcat4[4];
    __shared__ f4 sWe4[256];
    __shared__ f4 sbe4[8];
    int tid = threadIdx.x;
    int b = blockIdx.x;

    if (b % 3 != 0) {
        int h = b - b / 3 - 1;               // 0..781
        int e8 = h * 256 + tid;
        const int4v* dst4 = (const int4v*)(eidx + EE);
        int4v* rank4 = (int4v*)rank;
        #pragma unroll
        for (int hh = 0; hh < 2; hh++) {
            int i = e8 * 2 + hh;
            if (i * 4 < EE) {
                int4v d = __builtin_nontemporal_load(&dst4[i]);
                int4v r;
                r.x = atomicAdd(&deg[d.x], 1);
                r.y = atomicAdd(&deg[d.y], 1);
                r.z = atomicAdd(&deg[d.z], 1);
                r.w = atomicAdd(&deg[d.w], 1);
                rank4[i] = r;
            }
        }
        return;
    }

    {
        float* s;
        s=(float*)sWc4;   for(int i=tid;i<96;  i+=256) s[i]=par[O_WCONT+i];
        s=(float*)sbc4;   for(int i=tid;i<16;  i+=256) s[i]=par[O_BCONT+i];
        s=(float*)sTc4;   for(int i=tid;i<24;  i+=256) s[i]=par[O_TCHRG+i];
        s=(float*)sTp4;   for(int i=tid;i<56;  i+=256) s[i]=par[O_TPDG+i];
        s=(float*)sTv4;   for(int i=tid;i<64;  i+=256) s[i]=par[O_TPV+i];
        s=(float*)sWcat4; for(int i=tid;i<384; i+=256) s[i]=par[O_WCAT+i];
        s=(float*)sbcat4; for(int i=tid;i<16;  i+=256) s[i]=par[O_BCAT+i];
        s=(float*)sWe4;   for(int i=tid;i<1024;i+=256) s[i]=par[O_WENC+i];
        s=(float*)sbe4;   for(int i=tid;i<32;  i+=256) s[i]=par[O_BENC+i];
    }
    __syncthreads();

    int n = (b / 3) * 256 + tid;
    if (n >= NN) return;

    float x0,x1,x2,x3,x4,x5;
    if (*flag) {
        const float* xr = (const float*)xc + (size_t)n * 6;
        x0=xr[0]; x1=xr[1]; x2=xr[2]; x3=xr[3]; x4=xr[4]; x5=xr[5];
    } else {
        const unsigned* xr = (const unsigned*)xc + (size_t)n * 3;
        unsigned w0=xr[0], w1=xr[1], w2=xr[2];
        x0=__uint_as_float(w0<<16); x1=__uint_as_float(w0 & 0xFFFF0000u);
        x2=__uint_as_float(w1<<16); x3=__uint_as_float(w1 & 0xFFFF0000u);
        x4=__uint_as_float(w2<<16); x5=__uint_as_float(w2 & 0xFFFF0000u);
    }

    f4 ec[4];
    #pragma unroll
    for (int g = 0; g < 4; g++) {
        f4 a = sbc4[g];
        a += x0 * sWc4[0*4+g]; a += x1 * sWc4[1*4+g]; a += x2 * sWc4[2*4+g];
        a += x3 * sWc4[3*4+g]; a += x4 * sWc4[4*4+g]; a += x5 * sWc4[5*4+g];
        ec[g] = elu4(a);
    }

    int c0 = x_cat[n*3+0], c1 = x_cat[n*3+1], c2 = x_cat[n*3+2];
    int a0 = c0 < 0 ? -c0 : c0;
    int pi = (a0==1)?0:(a0==2)?1:(a0==11)?2:(a0==13)?3:(a0==22)?4:(a0==130)?5:6;
    int ci = c1 + 1;

    f4 t0a = sTc4[ci*2],  t0b = sTc4[ci*2+1];
    f4 t1a = sTp4[pi*2],  t1b = sTp4[pi*2+1];
    f4 t2a = sTv4[c2*2],  t2b = sTv4[c2*2+1];

    f4 ecat[4];
    #pragma unroll
    for (int g = 0; g < 4; g++) {
        f4 a = sbcat4[g];
        #pragma unroll
        for (int k = 0; k < 4; k++) a += t0a[k] * sWcat4[(k     )*4+g];
        #pragma unroll
        for (int k = 0; k < 4; k++) a += t0b[k] * sWcat4[(4 + k )*4+g];
        #pragma unroll
        for (int k = 0; k < 4; k++) a += t1a[k] * sWcat4[(8 + k )*4+g];
        #pragma unroll
        for (int k = 0; k < 4; k++) a += t1b[k] * sWcat4[(12 + k)*4+g];
        #pragma unroll
        for (int k = 0; k < 4; k++) a += t2a[k] * sWcat4[(16 + k)*4+g];
        #pragma unroll
        for (int k = 0; k < 4; k++) a += t2b[k] * sWcat4[(20 + k)*4+g];
        ecat[g] = elu4(a);
    }

    unsigned ob[16];
    #pragma unroll
    for (int cg = 0; cg < 8; cg++) {
        f4 a = sbe4[cg];
        #pragma unroll
        for (int kg = 0; kg < 4; kg++)
            #pragma unroll
            for (int k = 0; k < 4; k++)
                a += ecat[kg][k] * sWe4[(kg*4+k)*8 + cg];
        #pragma unroll
        for (int kg = 0; kg < 4; kg++)
            #pragma unroll
            for (int k = 0; k < 4; k++)
                a += ec[kg][k] * sWe4[(16 + kg*4+k)*8 + cg];
        f4 r = elu4(a);
        ob[cg*2]   = pack2(r.x, r.y);
        ob[cg*2+1] = pack2(r.z, r.w);
    }
    u4v* o = (u4v*)(embb + (size_t)n * 16);
    #pragma unroll
    for (int g = 0; g < 4; g++)
        o[g] = (u4v){ob[g*4], ob[g*4+1], ob[g*4+2], ob[g*4+3]};
}

// ---------------- fused B: scanA (blocks < NB_SCAN, last one also does scanB) | stats1 (512 blocks) ----------------
__global__ __launch_bounds__(256) void k_fusedB(
    const int* __restrict__ deg, int* __restrict__ rowp, int* __restrict__ bsum,
    const unsigned int* __restrict__ embb, float* __restrict__ stats,
    int* __restrict__ done)
{
    __shared__ int s[256];
    __shared__ int s2[512];
    __shared__ float ls[64];
    __shared__ int isLast;
    int tid = threadIdx.x;
    int b = blockIdx.x;
    if (b < NB_SCAN) {
        int i = b * 256 + tid;
        int v = (i < NN) ? deg[i] : 0;
        s[tid] = v;
        __syncthreads();
        for (int off = 1; off < 256; off <<= 1) {
            int x = (tid >= off) ? s[tid - off] : 0;
            __syncthreads();
            s[tid] += x;
            __syncthreads();
        }
        if (i < NN) rowp[i] = s[tid] - v;
        if (tid == 255) bsum[b] = s[255];
        // decoupled completion: last-finishing block performs scanB inline
        __syncthreads();
        if (tid == 0) {
            __threadfence();
            isLast = (atomicAdd(done, 1) == NB_SCAN - 1) ? 1 : 0;
        }
        __syncthreads();
        if (isLast) {
            __threadfence();   // acquire: see all blocks' bsum
            int v0 = (tid < NB_SCAN) ? bsum[tid] : 0;
            int v1 = (tid + 256 < NB_SCAN) ? bsum[tid + 256] : 0;
            s2[tid] = v0;
            s2[tid + 256] = v1;
            __syncthreads();
            for (int off = 1; off < 512; off <<= 1) {
                int a0 = (tid >= off) ? s2[tid - off] : 0;
                int a1 = (tid + 256 >= off) ? s2[tid + 256 - off] : 0;
                __syncthreads();
                s2[tid] += a0;
                s2[tid + 256] += a1;
                __syncthreads();
            }
            if (tid < NB_SCAN) bsum[tid] = s2[tid] - v0;
            if (tid + 256 < NB_SCAN) bsum[tid + 256] = s2[tid + 256] - v1;
        }
        return;
    }
    // stats1 over bf16 emb
    if (tid < 64) ls[tid] = 0.0f;
    __syncthreads();
    int sb = b - NB_SCAN;
    int idx = sb * 256 + tid;
    int stride = 512 * 256;             // multiple of 16 -> u32 slot fixed per thread
    int c2 = idx & 15;                  // u32 slot = channels 2*c2, 2*c2+1
    float s0 = 0.0f, q0 = 0.0f, s1 = 0.0f, q1 = 0.0f;
    for (int i = idx; i < NN * 16; i += stride) {
        unsigned v = embb[i];
        float a = bf(v & 0xFFFFu);
        float bb = bf(v >> 16);
        s0 += a; q0 += a * a;
        s1 += bb; q1 += bb * bb;
    }
    atomicAdd(&ls[2*c2], s0);
    atomicAdd(&ls[2*c2+1], s1);
    atomicAdd(&ls[32 + 2*c2], q0);
    atomicAdd(&ls[32 + 2*c2+1], q1);
    __syncthreads();
    if (tid < 64) atomicAdd(&stats[tid], ls[tid]);
}

// ---------------- fused C: scanC->deg (b%4==0) | pq (b%4==1, bf16 in/out) | scatter (b%4 in {2,3}) ----------------
__global__ __launch_bounds__(256, 1) void k_fusedC(
    const int* __restrict__ rowp, const int* __restrict__ bsum,
    int* __restrict__ degout,
    const float* __restrict__ par, const float* __restrict__ stats,
    const unsigned int* __restrict__ embb, unsigned int* __restrict__ Pb,
    unsigned int* __restrict__ Qb,
    const int* __restrict__ eidx, const int* __restrict__ rank,
    int* __restrict__ srcl)
{
    __shared__ f4 sWP4[256], sWQ4[256];
    __shared__ f4 sbP4[8], sbQ4[8];
    __shared__ float ssc[32], ssh[32];
    int tid = threadIdx.x;
    int b = blockIdx.x;
    int m4 = b & 3;

    if (m4 == 0) {
        int c = b >> 2;
        int i = c * 256 + tid;
        if (i < NN) degout[i] = rowp[i] + bsum[c];
        return;
    }
    if (m4 >= 2) {
        int sc = (b >> 2) * 2 + (m4 - 2);     // 0..781
        int e8 = sc * 256 + tid;
        const int4v* src4 = (const int4v*)eidx;
        const int4v* dst4 = (const int4v*)(eidx + EE);
        const int4v* rnk4 = (const int4v*)rank;
        #pragma unroll
        for (int h = 0; h < 2; h++) {
            int i = e8 * 2 + h;
            if (i * 4 < EE) {
                int4v s = __builtin_nontemporal_load(&src4[i]);
                int4v d = __builtin_nontemporal_load(&dst4[i]);
                int4v r = __builtin_nontemporal_load(&rnk4[i]);
                __builtin_nontemporal_store(s.x, &srcl[rowp[d.x] + bsum[d.x >> 8] + r.x]);
                __builtin_nontemporal_store(s.y, &srcl[rowp[d.y] + bsum[d.y >> 8] + r.y]);
                __builtin_nontemporal_store(s.z, &srcl[rowp[d.z] + bsum[d.z >> 8] + r.z]);
                __builtin_nontemporal_store(s.w, &srcl[rowp[d.w] + bsum[d.w >> 8] + r.w]);
            }
        }
        return;
    }

    // ---- pq path (b%4==1) ----
    if (tid < 32) {
        float mu  = stats[tid] * (1.0f / NN);
        float var = stats[32 + tid] * (1.0f / NN) - mu * mu;
        float s   = par[O_GALL + tid] * rsqrtf(var + 1e-5f);
        ssc[tid] = s;
        ssh[tid] = par[O_BEALL + tid] - mu * s;
    }
    __syncthreads();
    {
        float* wp = (float*)sWP4;
        float* wq = (float*)sWQ4;
        for (int e = tid; e < 1024; e += 256) {
            int k = e >> 5;
            float w1 = par[O_WMSG + e];
            float w2 = par[O_WMSG + 1024 + e];
            wp[e] = ssc[k] * (w1 - w2);
            wq[e] = ssc[k] * w2;
        }
    }
    if (tid < 32) {
        float aP = par[O_BMSG + tid], aQ = 0.0f;
        for (int k = 0; k < 32; k++) {
            float w1 = par[O_WMSG + k*32 + tid];
            float w2 = par[O_WMSG + (k+32)*32 + tid];
            aP += ssh[k] * (w1 - w2);
            aQ += ssh[k] * w2;
        }
        ((float*)sbP4)[tid] = aP;
        ((float*)sbQ4)[tid] = aQ;
    }
    __syncthreads();

    int n = (b >> 2) * 256 + tid;
    if (n >= NN) return;

    const u4v* er = (const u4v*)(embb + (size_t)n * 16);
    f4 e[8];
    #pragma unroll
    for (int g = 0; g < 4; g++) {
        u4v q = er[g];
        unpack8(q, e[g*2], e[g*2+1]);
    }

    #pragma unroll
    for (int cg = 0; cg < 8; cg++) {
        f4 aP = sbP4[cg];
        f4 aQ = sbQ4[cg];
        #pragma unroll
        for (int kg = 0; kg < 8; kg++)
            #pragma unroll
            for (int k = 0; k < 4; k++) {
                float ek = e[kg][k];
                aP += ek * sWP4[(kg*4+k)*8 + cg];
                aQ += ek * sWQ4[(kg*4+k)*8 + cg];
            }
        Pb[(size_t)n * 16 + cg * 2]     = pack2(aP.x, aP.y);
        Pb[(size_t)n * 16 + cg * 2 + 1] = pack2(aP.z, aP.w);
        Qb[(size_t)n * 16 + cg * 2]     = pack2(aQ.x, aQ.y);
        Qb[(size_t)n * 16 + cg * 2 + 1] = pack2(aQ.z, aQ.w);
    }
}

// ---------------- gather-max (wave/node, 16 slices x 4 lanes x 16B bf16) + fused stats2 ----------------
__global__ __launch_bounds__(256) void k_gather(
    const int* __restrict__ rowp, const int* __restrict__ srcl,
    const unsigned int* __restrict__ Qb, const unsigned int* __restrict__ Pb,
    unsigned int* __restrict__ aggb, float* __restrict__ stats2)
{
    __shared__ float ls[64];
    int tid = threadIdx.x;
    if (tid < 64) ls[tid] = 0.0f;
    __syncthreads();
    int lane = tid & 63;
    int wv0 = blockIdx.x * 4 + (tid >> 6);
    int slice = lane >> 2;               // 0..15 edge slice
    int cg    = lane & 3;                // 16B (8 channels) per lane
    for (int n = wv0; n < NN; n += GB * 4) {
        int beg = rowp[n];
        int end = (n + 1 < NN) ? rowp[n + 1] : EE;
        f4 m0 = {-INFINITY, -INFINITY, -INFINITY, -INFINITY};
        f4 m1 = m0;
        for (int e = beg + slice; e < end; e += 16) {
            int s = __builtin_nontemporal_load(&srcl[e]);
            u4v q = *(const u4v*)(Qb + (size_t)s * 16 + cg * 4);
            f4 a, bb;
            unpack8(q, a, bb);
            m0.x = fmaxf(m0.x, a.x);  m0.y = fmaxf(m0.y, a.y);
            m0.z = fmaxf(m0.z, a.z);  m0.w = fmaxf(m0.w, a.w);
            m1.x = fmaxf(m1.x, bb.x); m1.y = fmaxf(m1.y, bb.y);
            m1.z = fmaxf(m1.z, bb.z); m1.w = fmaxf(m1.w, bb.w);
        }
        #pragma unroll
        for (int off = 4; off < 64; off <<= 1) {
            m0.x = fmaxf(m0.x, __shfl_xor(m0.x, off));
            m0.y = fmaxf(m0.y, __shfl_xor(m0.y, off));
            m0.z = fmaxf(m0.z, __shfl_xor(m0.z, off));
            m0.w = fmaxf(m0.w, __shfl_xor(m0.w, off));
            m1.x = fmaxf(m1.x, __shfl_xor(m1.x, off));
            m1.y = fmaxf(m1.y, __shfl_xor(m1.y, off));
            m1.z = fmaxf(m1.z, __shfl_xor(m1.z, off));
            m1.w = fmaxf(m1.w, __shfl_xor(m1.w, off));
        }
        if (lane < 4) {
            f4 o0, o1;
            if (end > beg) {
                u4v pv = *(const u4v*)(Pb + (size_t)n * 16 + lane * 4);
                f4 p0, p1;
                unpack8(pv, p0, p1);
                o0 = m0 + p0;
                o1 = m1 + p1;
            } else {
                o0 = (f4){0.f, 0.f, 0.f, 0.f};
                o1 = o0;
            }
            u4v ov;
            ov.x = pack2(o0.x, o0.y); ov.y = pack2(o0.z, o0.w);
            ov.z = pack2(o1.x, o1.y); ov.w = pack2(o1.z, o1.w);
            *(u4v*)(aggb + (size_t)n * 16 + lane * 4) = ov;
            #pragma unroll
            for (int k = 0; k < 4; k++) {
                atomicAdd(&ls[lane*8 + k], o0[k]);
                atomicAdd(&ls[lane*8 + 4 + k], o1[k]);
                atomicAdd(&ls[32 + lane*8 + k], o0[k]*o0[k]);
                atomicAdd(&ls[32 + lane*8 + 4 + k], o1[k]*o1[k]);
            }
        }
    }
    __syncthreads();
    if (tid < 64) atomicAdd(&stats2[tid], ls[tid]);
}

// ---------------- output MLP (bn1 & bn2 scales built in-block; bf16 inputs) ----------------
__global__ __launch_bounds__(256, 1) void k_out(
    const unsigned int* __restrict__ embb, const unsigned int* __restrict__ aggb,
    const float* __restrict__ par, const float* __restrict__ stats,
    const int* __restrict__ flag, void* __restrict__ out)
{
    __shared__ f4 sW14[128];
    __shared__ f4 sb14[4], sW24[4];
    __shared__ f4 sc14[8], sh14[8], sc24[8], sh24[8];
    __shared__ float sb2s;
    int tid = threadIdx.x;
    {
        float* s = (float*)sW14;
        for (int i = tid; i < 512; i += 256) s[i] = par[O_WOUT1 + i];
    }
    if (tid < 16) {
        ((float*)sb14)[tid] = par[O_BOUT1 + tid];
        ((float*)sW24)[tid] = par[O_WOUT2 + tid];
    }
    if (tid < 32) {
        float mu  = stats[tid] * (1.0f / NN);
        float var = stats[32 + tid] * (1.0f / NN) - mu * mu;
        float s   = par[O_GALL + tid] * rsqrtf(var + 1e-5f);
        ((float*)sc14)[tid] = s;
        ((float*)sh14)[tid] = par[O_BEALL + tid] - mu * s;
        float mu2  = stats[64 + tid] * (1.0f / NN);
        float var2 = stats[96 + tid] * (1.0f / NN) - mu2 * mu2;
        float s2   = par[O_GCONV + tid] * rsqrtf(var2 + 1e-5f);
        ((float*)sc24)[tid] = s2;
        ((float*)sh24)[tid] = par[O_BECONV + tid] - mu2 * s2;
    }
    if (tid == 0) sb2s = par[O_BOUT2];
    __syncthreads();

    int n = blockIdx.x * 256 + tid;
    if (n >= NN) return;

    const u4v* er = (const u4v*)(embb + (size_t)n * 16);
    const u4v* ar = (const u4v*)(aggb + (size_t)n * 16);
    f4 h[8];
    #pragma unroll
    for (int g = 0; g < 4; g++) {
        f4 e0, e1, a0, a1;
        unpack8(er[g], e0, e1);
        unpack8(ar[g], a0, a1);
        h[g*2]   = e0 * sc14[g*2]   + sh14[g*2]   + a0 * sc24[g*2]   + sh24[g*2];
        h[g*2+1] = e1 * sc14[g*2+1] + sh14[g*2+1] + a1 * sc24[g*2+1] + sh24[g*2+1];
    }
    f4 o1[4];
    #pragma unroll
    for (int g = 0; g < 4; g++) {
        f4 acc = sb14[g];
        #pragma unroll
        for (int kg = 0; kg < 8; kg++)
            #pragma unroll
            for (int k = 0; k < 4; k++)
                acc += h[kg][k] * sW14[(kg*4+k)*4 + g];
        o1[g] = elu4(acc);
    }
    float acc = sb2s;
    #pragma unroll
    for (int g = 0; g < 4; g++) {
        f4 p = o1[g] * sW24[g];
        acc += p.x + p.y + p.z + p.w;
    }

    if (*flag) ((float*)out)[n] = acc;
    else       ((bf16_t*)out)[n] = __float2bfloat16(acc);
}

extern "C" void kernel_launch(void* const* d_in, const int* in_sizes, int n_in,
                              void* d_out, int out_size, void* d_ws, size_t ws_size,
                              hipStream_t stream)
{
    const void* x_cont = d_in[0];
    const int* x_cat = (const int*)d_in[1];
    const int* eidx  = (const int*)d_in[2];

    float* ws    = (float*)d_ws;
    float* par   = ws + PARB;
    unsigned int* embb = (unsigned int*)(ws + EMB);
    unsigned int* Pb   = (unsigned int*)(ws + PBUF);
    unsigned int* Qb   = (unsigned int*)(ws + QBUF);
    unsigned int* aggb = (unsigned int*)(ws + ABUF);
    int*   rank  = (int*)(ws + ABUF);     // aliased: rank dead before agg written
    float* stats = ws + SOFF;
    int*   flagp = (int*)(stats + 128);
    int*   done  = (int*)(stats + 132);
    int*   deg   = (int*)(ws + DEG);      // deg, then FINAL row pointers
    int*   rowp  = (int*)(ws + ROWP);     // chunk-local scan
    int*   bsum  = (int*)(ws + BSUM);
    int*   srcl  = (int*)(ws + SRCL);

    InitArgs ia;
    for (int t = 0; t < 19; t++) ia.p[t] = d_in[4 + t];
    ia.par = par; ia.deg = deg; ia.stats = stats; ia.flagp = flagp;
    k_init<<<NB_SCAN, 256, 0, stream>>>(ia);

    k_fusedA<<<HB + NB_SCAN, 256, 0, stream>>>(eidx, deg, rank, x_cont, x_cat,
                                               par, flagp, embb);
    k_fusedB<<<NB_SCAN + 512, 256, 0, stream>>>(deg, rowp, bsum, embb, stats, done);
    k_fusedC<<<NB_SCAN * 4, 256, 0, stream>>>(rowp, bsum, deg, par, stats, embb, Pb, Qb,
                                              eidx, rank, srcl);
    k_gather<<<GB, 256, 0, stream>>>(deg, srcl, Qb, Pb, aggb, stats + 64);
    k_out<<<NB_SCAN, 256, 0, stream>>>(embb, aggb, par, stats, flagp, d_out);
}

// Round 12
// 410.985 us; speedup vs baseline: 1.0243x; 1.0243x over previous
//
#include <hip/hip_runtime.h>
#include <hip/hip_bf16.h>

#define NN 100000
#define EE 1600000
#define NB_SCAN 391   // ceil(NN/256)
#define HB 782        // hist/scatter block count (8 edges/thread)
#define GB 2048       // gather blocks total (split into 2 XCD-parity phases)

typedef __hip_bfloat16 bf16_t;
typedef int int4v __attribute__((ext_vector_type(4)));
typedef float f4 __attribute__((ext_vector_type(4)));
typedef unsigned int u4v __attribute__((ext_vector_type(4)));
typedef unsigned int u2v __attribute__((ext_vector_type(2)));

// ---- workspace layout (float offsets) ----
#define PARB  600000       // params fp32 4465
#define EMB   604480       // N*32 bf16 (N*16 u32)
#define PBUF  3804480      // N*32 bf16 P'
#define QBUF  7004480      // N*32 bf16 Q
#define ABUF  10204480     // N*32 agg bf16; aliased as rank[EE] before gather
#define SOFF  13404480     // stats fp32 [0:128), flag@128(int), done@132(int)
#define DEG   (SOFF + 256)           // deg, then FINAL row pointers
#define ROWP  (DEG + 100000)         // chunk-local exclusive scan
#define BSUM  (ROWP + 100002)
#define SRCL  (BSUM + 512)

// ---- param offsets inside PARB ----
#define O_WCONT 0
#define O_BCONT 96
#define O_TCHRG 112
#define O_TPDG  136
#define O_TPV   192
#define O_WCAT  256
#define O_BCAT  640
#define O_WENC  656
#define O_BENC  1680
#define O_GALL  1712
#define O_BEALL 1744
#define O_WMSG  1776
#define O_BMSG  3824
#define O_GCONV 3856
#define O_BECONV 3888
#define O_WOUT1 3920
#define O_BOUT1 4432
#define O_WOUT2 4448
#define O_BOUT2 4464
#define NPAR    4465

__device__ __forceinline__ float bf(unsigned u) {
    return __uint_as_float(u << 16);
}
__device__ __forceinline__ unsigned short f2bf(float x) {
    __hip_bfloat16 h = __float2bfloat16(x);   // RNE
    return *reinterpret_cast<unsigned short*>(&h);
}
__device__ __forceinline__ unsigned pack2(float a, float b) {
    return (unsigned)f2bf(a) | ((unsigned)f2bf(b) << 16);
}
__device__ __forceinline__ f4 elu4(f4 v) {
    f4 r;
    r.x = v.x > 0.0f ? v.x : expm1f(v.x);
    r.y = v.y > 0.0f ? v.y : expm1f(v.y);
    r.z = v.z > 0.0f ? v.z : expm1f(v.z);
    r.w = v.w > 0.0f ? v.w : expm1f(v.w);
    return r;
}
__device__ __forceinline__ void unpack8(u4v q, f4& a, f4& b) {
    a.x = bf(q.x & 0xFFFFu); a.y = bf(q.x >> 16);
    a.z = bf(q.y & 0xFFFFu); a.w = bf(q.y >> 16);
    b.x = bf(q.z & 0xFFFFu); b.y = bf(q.z >> 16);
    b.z = bf(q.w & 0xFFFFu); b.w = bf(q.w >> 16);
}
__device__ __forceinline__ f4 unpack4(u2v q) {
    f4 a;
    a.x = bf(q.x & 0xFFFFu); a.y = bf(q.x >> 16);
    a.z = bf(q.y & 0xFFFFu); a.w = bf(q.y >> 16);
    return a;
}

// ---------------- init ----------------
struct InitArgs {
    const void* p[19];
    float*      par;
    int*        deg;
    float*      stats;
    int*        flagp;
};

__global__ __launch_bounds__(256) void k_init(InitArgs a)
{
    __shared__ int sflag;
    const int offs[20] = {O_WCONT,O_BCONT,O_TCHRG,O_TPDG,O_TPV,O_WCAT,O_BCAT,O_WENC,
                          O_BENC,O_GALL,O_BEALL,O_WMSG,O_BMSG,O_GCONV,O_BECONV,
                          O_WOUT1,O_BOUT1,O_WOUT2,O_BOUT2,NPAR};
    int b = blockIdx.x, tid = threadIdx.x;
    int g = b * 256 + tid;
    if (g < NN) a.deg[g] = 0;
    if (b == 0) {
        if (tid < 136) a.stats[tid] = 0.0f;   // stats + flag + done
        __syncthreads();
        int bad = 0;
        if (tid < 64) {
            const unsigned short* w = (const unsigned short*)a.p[7];  // W_enc
            for (int i = tid; i < 1024; i += 64) {
                unsigned e = (w[i] >> 7) & 0xFFu;
                if (e >= 137u) bad = 1;
            }
        }
        unsigned long long m = __ballot(bad);
        if (tid == 0) { sflag = (m != 0ull) ? 1 : 0; *a.flagp = sflag; }
        __syncthreads();
        int f32 = sflag;
        for (int i = tid; i < NPAR; i += 256) {
            int t = 0;
            while (offs[t + 1] <= i) t++;
            int l = i - offs[t];
            const void* s = a.p[t];
            a.par[i] = f32 ? ((const float*)s)[l] : bf(((const unsigned short*)s)[l]);
        }
    }
}

// ---------------- fused A: hist (b%3!=0) | embed->bf16 (b%3==0) ----------------
__global__ __launch_bounds__(256, 1) void k_fusedA(
    const int* __restrict__ eidx, int* __restrict__ deg, int* __restrict__ rank,
    const void* __restrict__ xc, const int* __restrict__ x_cat,
    const float* __restrict__ par, const int* __restrict__ flag,
    unsigned int* __restrict__ embb)
{
    __shared__ f4 sWc4[24];
    __shared__ f4 sbc4[4];
    __shared__ f4 sTc4[6], sTp4[14], sTv4[16];
    __shared__ f4 sWcat4[96];
    __shared__ f4 sbcat4[4];
    __shared__ f4 sWe4[256];
    __shared__ f4 sbe4[8];
    int tid = threadIdx.x;
    int b = blockIdx.x;

    if (b % 3 != 0) {
        int h = b - b / 3 - 1;               // 0..781
        int e8 = h * 256 + tid;
        const int4v* dst4 = (const int4v*)(eidx + EE);
        int4v* rank4 = (int4v*)rank;
        #pragma unroll
        for (int hh = 0; hh < 2; hh++) {
            int i = e8 * 2 + hh;
            if (i * 4 < EE) {
                int4v d = __builtin_nontemporal_load(&dst4[i]);
                int4v r;
                r.x = atomicAdd(&deg[d.x], 1);
                r.y = atomicAdd(&deg[d.y], 1);
                r.z = atomicAdd(&deg[d.z], 1);
                r.w = atomicAdd(&deg[d.w], 1);
                rank4[i] = r;
            }
        }
        return;
    }

    {
        float* s;
        s=(float*)sWc4;   for(int i=tid;i<96;  i+=256) s[i]=par[O_WCONT+i];
        s=(float*)sbc4;   for(int i=tid;i<16;  i+=256) s[i]=par[O_BCONT+i];
        s=(float*)sTc4;   for(int i=tid;i<24;  i+=256) s[i]=par[O_TCHRG+i];
        s=(float*)sTp4;   for(int i=tid;i<56;  i+=256) s[i]=par[O_TPDG+i];
        s=(float*)sTv4;   for(int i=tid;i<64;  i+=256) s[i]=par[O_TPV+i];
        s=(float*)sWcat4; for(int i=tid;i<384; i+=256) s[i]=par[O_WCAT+i];
        s=(float*)sbcat4; for(int i=tid;i<16;  i+=256) s[i]=par[O_BCAT+i];
        s=(float*)sWe4;   for(int i=tid;i<1024;i+=256) s[i]=par[O_WENC+i];
        s=(float*)sbe4;   for(int i=tid;i<32;  i+=256) s[i]=par[O_BENC+i];
    }
    __syncthreads();

    int n = (b / 3) * 256 + tid;
    if (n >= NN) return;

    float x0,x1,x2,x3,x4,x5;
    if (*flag) {
        const float* xr = (const float*)xc + (size_t)n * 6;
        x0=xr[0]; x1=xr[1]; x2=xr[2]; x3=xr[3]; x4=xr[4]; x5=xr[5];
    } else {
        const unsigned* xr = (const unsigned*)xc + (size_t)n * 3;
        unsigned w0=xr[0], w1=xr[1], w2=xr[2];
        x0=__uint_as_float(w0<<16); x1=__uint_as_float(w0 & 0xFFFF0000u);
        x2=__uint_as_float(w1<<16); x3=__uint_as_float(w1 & 0xFFFF0000u);
        x4=__uint_as_float(w2<<16); x5=__uint_as_float(w2 & 0xFFFF0000u);
    }

    f4 ec[4];
    #pragma unroll
    for (int g = 0; g < 4; g++) {
        f4 a = sbc4[g];
        a += x0 * sWc4[0*4+g]; a += x1 * sWc4[1*4+g]; a += x2 * sWc4[2*4+g];
        a += x3 * sWc4[3*4+g]; a += x4 * sWc4[4*4+g]; a += x5 * sWc4[5*4+g];
        ec[g] = elu4(a);
    }

    int c0 = x_cat[n*3+0], c1 = x_cat[n*3+1], c2 = x_cat[n*3+2];
    int a0 = c0 < 0 ? -c0 : c0;
    int pi = (a0==1)?0:(a0==2)?1:(a0==11)?2:(a0==13)?3:(a0==22)?4:(a0==130)?5:6;
    int ci = c1 + 1;

    f4 t0a = sTc4[ci*2],  t0b = sTc4[ci*2+1];
    f4 t1a = sTp4[pi*2],  t1b = sTp4[pi*2+1];
    f4 t2a = sTv4[c2*2],  t2b = sTv4[c2*2+1];

    f4 ecat[4];
    #pragma unroll
    for (int g = 0; g < 4; g++) {
        f4 a = sbcat4[g];
        #pragma unroll
        for (int k = 0; k < 4; k++) a += t0a[k] * sWcat4[(k     )*4+g];
        #pragma unroll
        for (int k = 0; k < 4; k++) a += t0b[k] * sWcat4[(4 + k )*4+g];
        #pragma unroll
        for (int k = 0; k < 4; k++) a += t1a[k] * sWcat4[(8 + k )*4+g];
        #pragma unroll
        for (int k = 0; k < 4; k++) a += t1b[k] * sWcat4[(12 + k)*4+g];
        #pragma unroll
        for (int k = 0; k < 4; k++) a += t2a[k] * sWcat4[(16 + k)*4+g];
        #pragma unroll
        for (int k = 0; k < 4; k++) a += t2b[k] * sWcat4[(20 + k)*4+g];
        ecat[g] = elu4(a);
    }

    unsigned ob[16];
    #pragma unroll
    for (int cg = 0; cg < 8; cg++) {
        f4 a = sbe4[cg];
        #pragma unroll
        for (int kg = 0; kg < 4; kg++)
            #pragma unroll
            for (int k = 0; k < 4; k++)
                a += ecat[kg][k] * sWe4[(kg*4+k)*8 + cg];
        #pragma unroll
        for (int kg = 0; kg < 4; kg++)
            #pragma unroll
            for (int k = 0; k < 4; k++)
                a += ec[kg][k] * sWe4[(16 + kg*4+k)*8 + cg];
        f4 r = elu4(a);
        ob[cg*2]   = pack2(r.x, r.y);
        ob[cg*2+1] = pack2(r.z, r.w);
    }
    u4v* o = (u4v*)(embb + (size_t)n * 16);
    #pragma unroll
    for (int g = 0; g < 4; g++)
        o[g] = (u4v){ob[g*4], ob[g*4+1], ob[g*4+2], ob[g*4+3]};
}

// ---------------- fused B: scanA (+inline scanB by last block) | stats1 ----------------
__global__ __launch_bounds__(256) void k_fusedB(
    const int* __restrict__ deg, int* __restrict__ rowp, int* __restrict__ bsum,
    const unsigned int* __restrict__ embb, float* __restrict__ stats,
    int* __restrict__ done)
{
    __shared__ int s[256];
    __shared__ int s2[512];
    __shared__ float ls[64];
    __shared__ int isLast;
    int tid = threadIdx.x;
    int b = blockIdx.x;
    if (b < NB_SCAN) {
        int i = b * 256 + tid;
        int v = (i < NN) ? deg[i] : 0;
        s[tid] = v;
        __syncthreads();
        for (int off = 1; off < 256; off <<= 1) {
            int x = (tid >= off) ? s[tid - off] : 0;
            __syncthreads();
            s[tid] += x;
            __syncthreads();
        }
        if (i < NN) rowp[i] = s[tid] - v;
        if (tid == 255) bsum[b] = s[255];
        __syncthreads();
        if (tid == 0) {
            __threadfence();
            isLast = (atomicAdd(done, 1) == NB_SCAN - 1) ? 1 : 0;
        }
        __syncthreads();
        if (isLast) {
            __threadfence();
            int v0 = (tid < NB_SCAN) ? bsum[tid] : 0;
            int v1 = (tid + 256 < NB_SCAN) ? bsum[tid + 256] : 0;
            s2[tid] = v0;
            s2[tid + 256] = v1;
            __syncthreads();
            for (int off = 1; off < 512; off <<= 1) {
                int a0 = (tid >= off) ? s2[tid - off] : 0;
                int a1 = (tid + 256 >= off) ? s2[tid + 256 - off] : 0;
                __syncthreads();
                s2[tid] += a0;
                s2[tid + 256] += a1;
                __syncthreads();
            }
            if (tid < NB_SCAN) bsum[tid] = s2[tid] - v0;
            if (tid + 256 < NB_SCAN) bsum[tid + 256] = s2[tid + 256] - v1;
        }
        return;
    }
    if (tid < 64) ls[tid] = 0.0f;
    __syncthreads();
    int sb = b - NB_SCAN;
    int idx = sb * 256 + tid;
    int stride = 512 * 256;
    int c2 = idx & 15;
    float s0 = 0.0f, q0 = 0.0f, s1 = 0.0f, q1 = 0.0f;
    for (int i = idx; i < NN * 16; i += stride) {
        unsigned v = embb[i];
        float a = bf(v & 0xFFFFu);
        float bb = bf(v >> 16);
        s0 += a; q0 += a * a;
        s1 += bb; q1 += bb * bb;
    }
    atomicAdd(&ls[2*c2], s0);
    atomicAdd(&ls[2*c2+1], s1);
    atomicAdd(&ls[32 + 2*c2], q0);
    atomicAdd(&ls[32 + 2*c2+1], q1);
    __syncthreads();
    if (tid < 64) atomicAdd(&stats[tid], ls[tid]);
}

// ---------------- fused C: scanC->deg | pq (bf16) | scatter ----------------
__global__ __launch_bounds__(256, 1) void k_fusedC(
    const int* __restrict__ rowp, const int* __restrict__ bsum,
    int* __restrict__ degout,
    const float* __restrict__ par, const float* __restrict__ stats,
    const unsigned int* __restrict__ embb, unsigned int* __restrict__ Pb,
    unsigned int* __restrict__ Qb,
    const int* __restrict__ eidx, const int* __restrict__ rank,
    int* __restrict__ srcl)
{
    __shared__ f4 sWP4[256], sWQ4[256];
    __shared__ f4 sbP4[8], sbQ4[8];
    __shared__ float ssc[32], ssh[32];
    int tid = threadIdx.x;
    int b = blockIdx.x;
    int m4 = b & 3;

    if (m4 == 0) {
        int c = b >> 2;
        int i = c * 256 + tid;
        if (i < NN) degout[i] = rowp[i] + bsum[c];
        return;
    }
    if (m4 >= 2) {
        int sc = (b >> 2) * 2 + (m4 - 2);
        int e8 = sc * 256 + tid;
        const int4v* src4 = (const int4v*)eidx;
        const int4v* dst4 = (const int4v*)(eidx + EE);
        const int4v* rnk4 = (const int4v*)rank;
        #pragma unroll
        for (int h = 0; h < 2; h++) {
            int i = e8 * 2 + h;
            if (i * 4 < EE) {
                int4v s = __builtin_nontemporal_load(&src4[i]);
                int4v d = __builtin_nontemporal_load(&dst4[i]);
                int4v r = __builtin_nontemporal_load(&rnk4[i]);
                __builtin_nontemporal_store(s.x, &srcl[rowp[d.x] + bsum[d.x >> 8] + r.x]);
                __builtin_nontemporal_store(s.y, &srcl[rowp[d.y] + bsum[d.y >> 8] + r.y]);
                __builtin_nontemporal_store(s.z, &srcl[rowp[d.z] + bsum[d.z >> 8] + r.z]);
                __builtin_nontemporal_store(s.w, &srcl[rowp[d.w] + bsum[d.w >> 8] + r.w]);
            }
        }
        return;
    }

    // pq path
    if (tid < 32) {
        float mu  = stats[tid] * (1.0f / NN);
        float var = stats[32 + tid] * (1.0f / NN) - mu * mu;
        float s   = par[O_GALL + tid] * rsqrtf(var + 1e-5f);
        ssc[tid] = s;
        ssh[tid] = par[O_BEALL + tid] - mu * s;
    }
    __syncthreads();
    {
        float* wp = (float*)sWP4;
        float* wq = (float*)sWQ4;
        for (int e = tid; e < 1024; e += 256) {
            int k = e >> 5;
            float w1 = par[O_WMSG + e];
            float w2 = par[O_WMSG + 1024 + e];
            wp[e] = ssc[k] * (w1 - w2);
            wq[e] = ssc[k] * w2;
        }
    }
    if (tid < 32) {
        float aP = par[O_BMSG + tid], aQ = 0.0f;
        for (int k = 0; k < 32; k++) {
            float w1 = par[O_WMSG + k*32 + tid];
            float w2 = par[O_WMSG + (k+32)*32 + tid];
            aP += ssh[k] * (w1 - w2);
            aQ += ssh[k] * w2;
        }
        ((float*)sbP4)[tid] = aP;
        ((float*)sbQ4)[tid] = aQ;
    }
    __syncthreads();

    int n = (b >> 2) * 256 + tid;
    if (n >= NN) return;

    const u4v* er = (const u4v*)(embb + (size_t)n * 16);
    f4 e[8];
    #pragma unroll
    for (int g = 0; g < 4; g++) {
        u4v q = er[g];
        unpack8(q, e[g*2], e[g*2+1]);
    }

    #pragma unroll
    for (int cg = 0; cg < 8; cg++) {
        f4 aP = sbP4[cg];
        f4 aQ = sbQ4[cg];
        #pragma unroll
        for (int kg = 0; kg < 8; kg++)
            #pragma unroll
            for (int k = 0; k < 4; k++) {
                float ek = e[kg][k];
                aP += ek * sWP4[(kg*4+k)*8 + cg];
                aQ += ek * sWQ4[(kg*4+k)*8 + cg];
            }
        Pb[(size_t)n * 16 + cg * 2]     = pack2(aP.x, aP.y);
        Pb[(size_t)n * 16 + cg * 2 + 1] = pack2(aP.z, aP.w);
        Qb[(size_t)n * 16 + cg * 2]     = pack2(aQ.x, aQ.y);
        Qb[(size_t)n * 16 + cg * 2 + 1] = pack2(aQ.z, aQ.w);
    }
}

// ---------------- gather-max: XCD-parity channel-split ----------------
// Blocks with even (blockIdx%8) handle channels [0,16); odd handle [16,32).
// Each XCD's L2 then only caches a 3.2MB half of Q -> random reads become L2 hits.
// Correct regardless of actual block->XCD mapping (parity is a locality hint only).
__global__ __launch_bounds__(256) void k_gather(
    const int* __restrict__ rowp, const int* __restrict__ srcl,
    const unsigned int* __restrict__ Qb, const unsigned int* __restrict__ Pb,
    unsigned int* __restrict__ aggb, float* __restrict__ stats2)
{
    __shared__ float ls[64];
    int tid = threadIdx.x;
    if (tid < 64) ls[tid] = 0.0f;
    __syncthreads();
    int b = blockIdx.x;
    int phase = b & 1;                       // even/odd XCD parity (blockIdx%8 parity == blockIdx parity)
    int pidx  = b >> 1;                      // 0..GB/2-1 per phase
    int lane = tid & 63;
    int wv0 = pidx * 4 + (tid >> 6);
    int slice = lane >> 2;                   // 0..15 edge slice
    int cg    = lane & 3;                    // 4 channels (8B) per lane
    int qoff  = phase * 8 + cg * 2;          // u32 offset inside 16-u32 row
    for (int n = wv0; n < NN; n += (GB / 2) * 4) {
        int beg = rowp[n];
        int end = (n + 1 < NN) ? rowp[n + 1] : EE;
        f4 m = {-INFINITY, -INFINITY, -INFINITY, -INFINITY};
        for (int e = beg + slice; e < end; e += 16) {
            int s = __builtin_nontemporal_load(&srcl[e]);
            u2v q = *(const u2v*)(Qb + (size_t)s * 16 + qoff);
            f4 a = unpack4(q);
            m.x = fmaxf(m.x, a.x); m.y = fmaxf(m.y, a.y);
            m.z = fmaxf(m.z, a.z); m.w = fmaxf(m.w, a.w);
        }
        #pragma unroll
        for (int off = 4; off < 64; off <<= 1) {
            m.x = fmaxf(m.x, __shfl_xor(m.x, off));
            m.y = fmaxf(m.y, __shfl_xor(m.y, off));
            m.z = fmaxf(m.z, __shfl_xor(m.z, off));
            m.w = fmaxf(m.w, __shfl_xor(m.w, off));
        }
        if (lane < 4) {
            f4 o;
            if (end > beg) {
                u2v pv = __builtin_nontemporal_load(
                    (const u2v*)(Pb + (size_t)n * 16 + phase * 8 + lane * 2));
                o = m + unpack4(pv);
            } else {
                o = (f4){0.f, 0.f, 0.f, 0.f};
            }
            u2v ov;
            ov.x = pack2(o.x, o.y);
            ov.y = pack2(o.z, o.w);
            *(u2v*)(aggb + (size_t)n * 16 + phase * 8 + lane * 2) = ov;
            int c0 = phase * 16 + lane * 4;
            #pragma unroll
            for (int k = 0; k < 4; k++) {
                atomicAdd(&ls[c0 + k], o[k]);
                atomicAdd(&ls[32 + c0 + k], o[k] * o[k]);
            }
        }
    }
    __syncthreads();
    if (tid < 64) atomicAdd(&stats2[tid], ls[tid]);
}

// ---------------- output MLP ----------------
__global__ __launch_bounds__(256, 1) void k_out(
    const unsigned int* __restrict__ embb, const unsigned int* __restrict__ aggb,
    const float* __restrict__ par, const float* __restrict__ stats,
    const int* __restrict__ flag, void* __restrict__ out)
{
    __shared__ f4 sW14[128];
    __shared__ f4 sb14[4], sW24[4];
    __shared__ f4 sc14[8], sh14[8], sc24[8], sh24[8];
    __shared__ float sb2s;
    int tid = threadIdx.x;
    {
        float* s = (float*)sW14;
        for (int i = tid; i < 512; i += 256) s[i] = par[O_WOUT1 + i];
    }
    if (tid < 16) {
        ((float*)sb14)[tid] = par[O_BOUT1 + tid];
        ((float*)sW24)[tid] = par[O_WOUT2 + tid];
    }
    if (tid < 32) {
        float mu  = stats[tid] * (1.0f / NN);
        float var = stats[32 + tid] * (1.0f / NN) - mu * mu;
        float s   = par[O_GALL + tid] * rsqrtf(var + 1e-5f);
        ((float*)sc14)[tid] = s;
        ((float*)sh14)[tid] = par[O_BEALL + tid] - mu * s;
        float mu2  = stats[64 + tid] * (1.0f / NN);
        float var2 = stats[96 + tid] * (1.0f / NN) - mu2 * mu2;
        float s2   = par[O_GCONV + tid] * rsqrtf(var2 + 1e-5f);
        ((float*)sc24)[tid] = s2;
        ((float*)sh24)[tid] = par[O_BECONV + tid] - mu2 * s2;
    }
    if (tid == 0) sb2s = par[O_BOUT2];
    __syncthreads();

    int n = blockIdx.x * 256 + tid;
    if (n >= NN) return;

    const u4v* er = (const u4v*)(embb + (size_t)n * 16);
    const u4v* ar = (const u4v*)(aggb + (size_t)n * 16);
    f4 h[8];
    #pragma unroll
    for (int g = 0; g < 4; g++) {
        f4 e0, e1, a0, a1;
        unpack8(er[g], e0, e1);
        unpack8(ar[g], a0, a1);
        h[g*2]   = e0 * sc14[g*2]   + sh14[g*2]   + a0 * sc24[g*2]   + sh24[g*2];
        h[g*2+1] = e1 * sc14[g*2+1] + sh14[g*2+1] + a1 * sc24[g*2+1] + sh24[g*2+1];
    }
    f4 o1[4];
    #pragma unroll
    for (int g = 0; g < 4; g++) {
        f4 acc = sb14[g];
        #pragma unroll
        for (int kg = 0; kg < 8; kg++)
            #pragma unroll
            for (int k = 0; k < 4; k++)
                acc += h[kg][k] * sW14[(kg*4+k)*4 + g];
        o1[g] = elu4(acc);
    }
    float acc = sb2s;
    #pragma unroll
    for (int g = 0; g < 4; g++) {
        f4 p = o1[g] * sW24[g];
        acc += p.x + p.y + p.z + p.w;
    }

    if (*flag) ((float*)out)[n] = acc;
    else       ((bf16_t*)out)[n] = __float2bfloat16(acc);
}

extern "C" void kernel_launch(void* const* d_in, const int* in_sizes, int n_in,
                              void* d_out, int out_size, void* d_ws, size_t ws_size,
                              hipStream_t stream)
{
    const void* x_cont = d_in[0];
    const int* x_cat = (const int*)d_in[1];
    const int* eidx  = (const int*)d_in[2];

    float* ws    = (float*)d_ws;
    float* par   = ws + PARB;
    unsigned int* embb = (unsigned int*)(ws + EMB);
    unsigned int* Pb   = (unsigned int*)(ws + PBUF);
    unsigned int* Qb   = (unsigned int*)(ws + QBUF);
    unsigned int* aggb = (unsigned int*)(ws + ABUF);
    int*   rank  = (int*)(ws + ABUF);
    float* stats = ws + SOFF;
    int*   flagp = (int*)(stats + 128);
    int*   done  = (int*)(stats + 132);
    int*   deg   = (int*)(ws + DEG);
    int*   rowp  = (int*)(ws + ROWP);
    int*   bsum  = (int*)(ws + BSUM);
    int*   srcl  = (int*)(ws + SRCL);

    InitArgs ia;
    for (int t = 0; t < 19; t++) ia.p[t] = d_in[4 + t];
    ia.par = par; ia.deg = deg; ia.stats = stats; ia.flagp = flagp;
    k_init<<<NB_SCAN, 256, 0, stream>>>(ia);

    k_fusedA<<<HB + NB_SCAN, 256, 0, stream>>>(eidx, deg, rank, x_cont, x_cat,
                                               par, flagp, embb);
    k_fusedB<<<NB_SCAN + 512, 256, 0, stream>>>(deg, rowp, bsum, embb, stats, done);
    k_fusedC<<<NB_SCAN * 4, 256, 0, stream>>>(rowp, bsum, deg, par, stats, embb, Pb, Qb,
                                              eidx, rank, srcl);
    k_gather<<<GB, 256, 0, stream>>>(deg, srcl, Qb, Pb, aggb, stats + 64);
    k_out<<<NB_SCAN, 256, 0, stream>>>(embb, aggb, par, stats, flagp, d_out);
}